// Round 8
// baseline (575.677 us; speedup 1.0000x reference)
//
#include <hip/hip_runtime.h>
#include <math.h>

#define KD 200
#define CD 352
#define NSYS 8      // systems per block
#define NITER 40    // PCG iterations (rate ~0.75 => ~1e-5 rel)
#define LMB 0.01f

__device__ __forceinline__ float4 ld4(const float* p) { return *(const float4*)p; }
__device__ __forceinline__ void st4(float* p, float4 v) { *(float4*)p = v; }

// p-vector LDS layout: quad-c interleaved, P[(c>>2)*32 + s*4 + (c&3)]
#define PA(r, s) ((((r) >> 2) << 5) + ((s) << 2) + ((r) & 3))

// ---------------- Kernel 1: G = A A^T, R = B A^T (batched, tiled) ----------------
__global__ __launch_bounds__(256) void gemm_gr_kernel(
    const float* __restrict__ A, const float* __restrict__ B,
    float* __restrict__ G, float* __restrict__ R)
{
    __shared__ float As[32][33];
    __shared__ float Bs[32][33];
    const int tid = threadIdx.x;
    const int tx = tid & 15, ty = tid >> 4;
    const int z = blockIdx.z;
    const int b = z >> 1, which = z & 1;
    const float* Xb = (which ? B : A) + (size_t)b * KD * CD;
    const float* Ab = A + (size_t)b * KD * CD;
    float* O = (which ? R : G) + (size_t)b * KD * KD;
    const int tileM = blockIdx.y * 32;
    const int tileN = blockIdx.x * 32;

    const int lrow = tid >> 3;
    const int lc   = (tid & 7) * 4;

    float acc00 = 0.f, acc01 = 0.f, acc10 = 0.f, acc11 = 0.f;
    const int m0 = tileM + ty * 2, m1 = m0 + 1;
    const int n0 = tileN + tx * 2, n1 = n0 + 1;

    for (int kk = 0; kk < CD; kk += 32) {
        const int gm = tileM + lrow;
        const int gn = tileN + lrow;
        float4 va = make_float4(0.f, 0.f, 0.f, 0.f);
        float4 vb = make_float4(0.f, 0.f, 0.f, 0.f);
        if (gm < KD) va = *(const float4*)(Xb + (size_t)gm * CD + kk + lc);
        if (gn < KD) vb = *(const float4*)(Ab + (size_t)gn * CD + kk + lc);
        __syncthreads();
        As[lrow][lc + 0] = va.x; As[lrow][lc + 1] = va.y;
        As[lrow][lc + 2] = va.z; As[lrow][lc + 3] = va.w;
        Bs[lrow][lc + 0] = vb.x; Bs[lrow][lc + 1] = vb.y;
        Bs[lrow][lc + 2] = vb.z; Bs[lrow][lc + 3] = vb.w;
        __syncthreads();
        #pragma unroll
        for (int k = 0; k < 32; ++k) {
            float a0 = As[ty * 2][k], a1 = As[ty * 2 + 1][k];
            float b0 = Bs[tx * 2][k], b1 = Bs[tx * 2 + 1][k];
            acc00 = fmaf(a0, b0, acc00); acc01 = fmaf(a0, b1, acc01);
            acc10 = fmaf(a1, b0, acc10); acc11 = fmaf(a1, b1, acc11);
        }
    }
    if (m0 < KD) {
        if (n0 < KD) O[(size_t)m0 * KD + n0] = acc00;
        if (n1 < KD) O[(size_t)m0 * KD + n1] = acc01;
    }
    if (m1 < KD) {
        if (n0 < KD) O[(size_t)m1 * KD + n0] = acc10;
        if (n1 < KD) O[(size_t)m1 * KD + n1] = acc11;
    }
}

// ---------------- Kernel 2: batched Jacobi-PCG, register-resident state ----------------
// Thread (rg = tid>>3, s = tid&7) owns rows {rg, rg+64, rg+128, rg+192?} of system i0+s.
// x, r, q, lam, dinv live in registers. Only p is shared (LDS, 6.4 KB).
// Reductions: __shfl_xor over same-s lanes (offsets 8/16/32) + 64-entry LDS stage.
__global__ __launch_bounds__(512) void cg_kernel(
    const float* __restrict__ G, const float* __restrict__ R,
    const float* __restrict__ ex, const float* __restrict__ ey,
    float* __restrict__ out)
{
    __shared__ __align__(16) float P[50 * 32];   // 200 c x 8 sys, quad-c interleaved
    __shared__ float red_pq[64];
    __shared__ float red_rz[64];
    __shared__ float red[8];

    const int tid = threadIdx.x;
    const int blk = blockIdx.x;          // 0..199
    const int b = blk / 25;
    const int i0 = (blk - b * 25) * NSYS;
    const int bK = b * KD;
    const float* __restrict__ Gb = G + (size_t)b * KD * KD;

    const int s = tid & 7;
    const int rg = tid >> 3;             // 0..63
    const int w = tid >> 6, l = tid & 63;
    const bool has4 = (rg < 8);          // wave-uniform: wave 0 owns a 4th row

    // ---- scale = max(ex[b,:], ey[b,:]) ----
    float mxv = 0.f;
    if (tid < KD) mxv = fmaxf(ex[bK + tid], ey[bK + tid]);
    #pragma unroll
    for (int off = 32; off > 0; off >>= 1)
        mxv = fmaxf(mxv, __shfl_down(mxv, off, 64));
    if (l == 0) red[w] = mxv;
    __syncthreads();
    float scale = red[0];
    #pragma unroll
    for (int wv = 1; wv < 8; ++wv) scale = fmaxf(scale, red[wv]);
    const float inv_scale = 1.0f / scale;

    // ---- rows, lam, dinv (registers) ----
    const int r0 = rg, r1 = rg + 64, r2 = rg + 128, r3v = has4 ? rg + 192 : 0;
    const float eyi = ey[bK + i0 + s] * inv_scale;
    const float e2 = sqrtf(eyi);
    float lam0, lam1, lam2, lam3;
    {
        float exj, e1, dn, re;
        exj = ex[bK + r0] * inv_scale; e1 = sqrtf(exj); dn = exj + eyi; re = e2 - e1;
        lam0 = LMB * ((re * re + 1.f) / (dn * dn));
        exj = ex[bK + r1] * inv_scale; e1 = sqrtf(exj); dn = exj + eyi; re = e2 - e1;
        lam1 = LMB * ((re * re + 1.f) / (dn * dn));
        exj = ex[bK + r2] * inv_scale; e1 = sqrtf(exj); dn = exj + eyi; re = e2 - e1;
        lam2 = LMB * ((re * re + 1.f) / (dn * dn));
        exj = ex[bK + r3v] * inv_scale; e1 = sqrtf(exj); dn = exj + eyi; re = e2 - e1;
        lam3 = LMB * ((re * re + 1.f) / (dn * dn));
    }
    const float dv0 = 1.f / (Gb[(size_t)r0 * KD + r0] + lam0);
    const float dv1 = 1.f / (Gb[(size_t)r1 * KD + r1] + lam1);
    const float dv2 = 1.f / (Gb[(size_t)r2 * KD + r2] + lam2);
    const float dv3 = 1.f / (Gb[(size_t)r3v * KD + r3v] + lam3);

    // ---- r = b, x = 0, p = z = dinv*r, rz = r.z ----
    const float* __restrict__ Rrow = R + (size_t)(bK + i0 + s) * KD;
    float rr0 = Rrow[r0], rr1 = Rrow[r1], rr2 = Rrow[r2];
    float rr3 = has4 ? Rrow[r3v] : 0.f;
    float x0 = 0.f, x1 = 0.f, x2 = 0.f, x3 = 0.f;
    {
        const float z0 = rr0 * dv0, z1 = rr1 * dv1, z2 = rr2 * dv2, z3 = rr3 * dv3;
        P[PA(r0, s)] = z0;
        P[PA(r1, s)] = z1;
        P[PA(r2, s)] = z2;
        if (has4) P[PA(r3v, s)] = z3;
        float rzp = rr0 * z0 + rr1 * z1 + rr2 * z2 + rr3 * z3;
        #pragma unroll
        for (int off = 8; off < 64; off <<= 1)
            rzp += __shfl_xor(rzp, off, 64);
        if (l < 8) red_rz[w * 8 + l] = rzp;
    }
    __syncthreads();
    float rz = 0.f;
    #pragma unroll
    for (int wv = 0; wv < 8; ++wv) rz += red_rz[wv * 8 + s];

    const float* __restrict__ g0r = Gb + (size_t)r0 * KD;
    const float* __restrict__ g1r = Gb + (size_t)r1 * KD;
    const float* __restrict__ g2r = Gb + (size_t)r2 * KD;
    const float* __restrict__ g3r = Gb + (size_t)r3v * KD;

    // ================= PCG main loop =================
    for (int k = 0; k < NITER; ++k) {
        // ---- matvec: qa = G * p (rows owned in registers) ----
        float qa0 = 0.f, qa1 = 0.f, qa2 = 0.f, qa3 = 0.f;
        #pragma unroll 5
        for (int cq = 0; cq < 50; ++cq) {
            const float4 pv = ld4(&P[cq * 32 + s * 4]);
            float4 ga;
            ga = ld4(g0r + cq * 4);
            qa0 = fmaf(ga.x, pv.x, qa0); qa0 = fmaf(ga.y, pv.y, qa0);
            qa0 = fmaf(ga.z, pv.z, qa0); qa0 = fmaf(ga.w, pv.w, qa0);
            ga = ld4(g1r + cq * 4);
            qa1 = fmaf(ga.x, pv.x, qa1); qa1 = fmaf(ga.y, pv.y, qa1);
            qa1 = fmaf(ga.z, pv.z, qa1); qa1 = fmaf(ga.w, pv.w, qa1);
            ga = ld4(g2r + cq * 4);
            qa2 = fmaf(ga.x, pv.x, qa2); qa2 = fmaf(ga.y, pv.y, qa2);
            qa2 = fmaf(ga.z, pv.z, qa2); qa2 = fmaf(ga.w, pv.w, qa2);
            if (has4) {
                ga = ld4(g3r + cq * 4);
                qa3 = fmaf(ga.x, pv.x, qa3); qa3 = fmaf(ga.y, pv.y, qa3);
                qa3 = fmaf(ga.z, pv.z, qa3); qa3 = fmaf(ga.w, pv.w, qa3);
            }
        }

        // ---- own p, full q (+ lam*p), pq partial ----
        const float p0 = P[PA(r0, s)];
        const float p1 = P[PA(r1, s)];
        const float p2 = P[PA(r2, s)];
        const float p3 = has4 ? P[PA(r3v, s)] : 0.f;
        const float q0 = qa0 + lam0 * p0;
        const float q1 = qa1 + lam1 * p1;
        const float q2 = qa2 + lam2 * p2;
        const float q3 = qa3 + lam3 * p3;
        float pqp = p0 * q0 + p1 * q1 + p2 * q2 + p3 * q3;
        #pragma unroll
        for (int off = 8; off < 64; off <<= 1)
            pqp += __shfl_xor(pqp, off, 64);
        if (l < 8) red_pq[w * 8 + l] = pqp;
        __syncthreads();
        float pq = 0.f;
        #pragma unroll
        for (int wv = 0; wv < 8; ++wv) pq += red_pq[wv * 8 + s];
        const float alpha = rz / pq;

        // ---- x += alpha p; r -= alpha q; rz_new ----
        x0 = fmaf(alpha, p0, x0); rr0 = fmaf(-alpha, q0, rr0);
        x1 = fmaf(alpha, p1, x1); rr1 = fmaf(-alpha, q1, rr1);
        x2 = fmaf(alpha, p2, x2); rr2 = fmaf(-alpha, q2, rr2);
        x3 = fmaf(alpha, p3, x3); rr3 = fmaf(-alpha, q3, rr3);
        float rzp = rr0 * rr0 * dv0 + rr1 * rr1 * dv1 + rr2 * rr2 * dv2 + rr3 * rr3 * dv3;
        #pragma unroll
        for (int off = 8; off < 64; off <<= 1)
            rzp += __shfl_xor(rzp, off, 64);
        if (l < 8) red_rz[w * 8 + l] = rzp;
        __syncthreads();
        float rzn = 0.f;
        #pragma unroll
        for (int wv = 0; wv < 8; ++wv) rzn += red_rz[wv * 8 + s];
        const float beta = rzn / rz;
        rz = rzn;

        // ---- p = dinv*r + beta*p ----
        if (k + 1 < NITER) {
            P[PA(r0, s)] = fmaf(beta, p0, rr0 * dv0);
            P[PA(r1, s)] = fmaf(beta, p1, rr1 * dv1);
            P[PA(r2, s)] = fmaf(beta, p2, rr2 * dv2);
            if (has4) P[PA(r3v, s)] = fmaf(beta, p3, rr3 * dv3);
            __syncthreads();
        }
    }

    // ---- store x ----
    float* __restrict__ Orow = out + (size_t)(bK + i0 + s) * KD;
    Orow[r0] = x0;
    Orow[r1] = x1;
    Orow[r2] = x2;
    if (has4) Orow[r3v] = x3;
}

extern "C" void kernel_launch(void* const* d_in, const int* in_sizes, int n_in,
                              void* d_out, int out_size, void* d_ws, size_t ws_size,
                              hipStream_t stream) {
    const float* A  = (const float*)d_in[0];
    const float* B  = (const float*)d_in[1];
    const float* ex = (const float*)d_in[2];
    const float* ey = (const float*)d_in[3];
    float* out = (float*)d_out;

    float* G = (float*)d_ws;
    float* R = G + 8 * KD * KD;

    dim3 grid1(7, 7, 16);
    gemm_gr_kernel<<<grid1, 256, 0, stream>>>(A, B, G, R);

    cg_kernel<<<200, 512, 0, stream>>>(G, R, ex, ey, out);
}

// Round 11
// 298.912 us; speedup vs baseline: 1.9259x; 1.9259x over previous
//
#include <hip/hip_runtime.h>
#include <math.h>

#define KD 200
#define CD 352
#define NITER 40
#define LMB 0.01f

__device__ __forceinline__ float4 ld4(const float* p) { return *(const float4*)p; }
__device__ __forceinline__ void st4(float* p, float4 v) { *(float4*)p = v; }
__device__ __forceinline__ float rdlane(float v, int lane) {
    return __int_as_float(__builtin_amdgcn_readlane(__float_as_int(v), lane));
}

// ---------------- Kernel 1: G = A A^T, R = B A^T (batched, tiled) ----------------
__global__ __launch_bounds__(256) void gemm_gr_kernel(
    const float* __restrict__ A, const float* __restrict__ B,
    float* __restrict__ G, float* __restrict__ R)
{
    __shared__ float As[32][33];
    __shared__ float Bs[32][33];
    const int tid = threadIdx.x;
    const int tx = tid & 15, ty = tid >> 4;
    const int z = blockIdx.z;
    const int b = z >> 1, which = z & 1;
    const float* Xb = (which ? B : A) + (size_t)b * KD * CD;
    const float* Ab = A + (size_t)b * KD * CD;
    float* O = (which ? R : G) + (size_t)b * KD * KD;
    const int tileM = blockIdx.y * 32;
    const int tileN = blockIdx.x * 32;

    const int lrow = tid >> 3;
    const int lc   = (tid & 7) * 4;

    float acc00 = 0.f, acc01 = 0.f, acc10 = 0.f, acc11 = 0.f;
    const int m0 = tileM + ty * 2, m1 = m0 + 1;
    const int n0 = tileN + tx * 2, n1 = n0 + 1;

    for (int kk = 0; kk < CD; kk += 32) {
        const int gm = tileM + lrow;
        const int gn = tileN + lrow;
        float4 va = make_float4(0.f, 0.f, 0.f, 0.f);
        float4 vb = make_float4(0.f, 0.f, 0.f, 0.f);
        if (gm < KD) va = *(const float4*)(Xb + (size_t)gm * CD + kk + lc);
        if (gn < KD) vb = *(const float4*)(Ab + (size_t)gn * CD + kk + lc);
        __syncthreads();
        As[lrow][lc + 0] = va.x; As[lrow][lc + 1] = va.y;
        As[lrow][lc + 2] = va.z; As[lrow][lc + 3] = va.w;
        Bs[lrow][lc + 0] = vb.x; Bs[lrow][lc + 1] = vb.y;
        Bs[lrow][lc + 2] = vb.z; Bs[lrow][lc + 3] = vb.w;
        __syncthreads();
        #pragma unroll
        for (int k = 0; k < 32; ++k) {
            float a0 = As[ty * 2][k], a1 = As[ty * 2 + 1][k];
            float b0 = Bs[tx * 2][k], b1 = Bs[tx * 2 + 1][k];
            acc00 = fmaf(a0, b0, acc00); acc01 = fmaf(a0, b1, acc01);
            acc10 = fmaf(a1, b0, acc10); acc11 = fmaf(a1, b1, acc11);
        }
    }
    if (m0 < KD) {
        if (n0 < KD) O[(size_t)m0 * KD + n0] = acc00;
        if (n1 < KD) O[(size_t)m0 * KD + n1] = acc01;
    }
    if (m1 < KD) {
        if (n0 < KD) O[(size_t)m1 * KD + n0] = acc10;
        if (n1 < KD) O[(size_t)m1 * KD + n1] = acc11;
    }
}

// ------------- Kernel 2: batched standard PCG, 8 systems/block -------------
// Matvec (on p): lane l (l<50) of wave w owns rows {l, l+50, l+100, l+150}; wave w
// covers column-chunks jc = w, w+8, w+16 (+24 for w==0). G reads coalesced
// (column-wise, symmetric); p broadcast via readlane->SGPR from one packed LDS read.
// BRANCH-FREE matvec: lanes 50..63 clamp their G column to 49 and compute throwaway
// accumulators (store masked) so the P read feeding readlane is defined in ALL lanes
// (guarding it caused the R9/R10 failures: compiler sank the load into the branch,
// leaving readlane sources 50..63 undefined).
// State thread tid<400 = (row r=tid>>1, quad sq=tid&1) keeps x,r,p,lam,dinv,rz
// for (row r, systems sq*4..sq*4+3) in REGISTERS. Direct dots (standard PCG).
__global__ __launch_bounds__(512) void cg_kernel(
    const float* __restrict__ G, const float* __restrict__ R,
    const float* __restrict__ ex, const float* __restrict__ ey,
    float* __restrict__ out)
{
    __shared__ __align__(16) float P[KD * 8];          // p[c][s]
    __shared__ __align__(16) float PART[8 * KD * 8];   // [w][row][s], 51.2 KB
    __shared__ float WP1[8][8];                        // pq (or rz0) partials [w][sq*4+j]
    __shared__ float WP2[8][8];                        // rz partials
    __shared__ float red8[8];

    const int tid = threadIdx.x;
    const int w = tid >> 6, l = tid & 63;
    const int blk = blockIdx.x;
    const int b = blk / 25;
    const int i0 = (blk - b * 25) * 8;
    const int bK = b * KD;
    const float* __restrict__ Gb = G + (size_t)b * KD * KD;

    // ---- scale = max(ex[b,:], ey[b,:]) ----
    float mxv = 0.f;
    if (tid < KD) mxv = fmaxf(ex[bK + tid], ey[bK + tid]);
    #pragma unroll
    for (int off = 32; off > 0; off >>= 1)
        mxv = fmaxf(mxv, __shfl_down(mxv, off, 64));
    if (l == 0) red8[w] = mxv;
    __syncthreads();
    float scale = red8[0];
    #pragma unroll
    for (int wv = 1; wv < 8; ++wv) scale = fmaxf(scale, red8[wv]);
    const float inv_scale = 1.0f / scale;

    // ---- state init (registers) ----
    const bool stid = tid < 400;
    const int r = tid >> 1, sq = tid & 1;
    float lam[4], dinv[4], rr[4], xx[4], pp[4], rz4[4];
    if (stid) {
        const float exj = ex[bK + r] * inv_scale;
        const float e1 = sqrtf(exj);
        const float gdiag = Gb[(size_t)r * KD + r];
        const float* __restrict__ Rb = R + (size_t)(bK + i0 + sq * 4) * KD + r;
        #pragma unroll
        for (int j = 0; j < 4; ++j) {
            const float eyi = ey[bK + i0 + sq * 4 + j] * inv_scale;
            const float e2 = sqrtf(eyi);
            const float dn = exj + eyi;
            const float re = e2 - e1;
            lam[j] = LMB * ((re * re + 1.f) / (dn * dn));
            dinv[j] = 1.f / (gdiag + lam[j]);
            rr[j] = Rb[(size_t)j * KD];
            pp[j] = rr[j] * dinv[j];      // p0 = z0
            xx[j] = 0.f;
        }
        st4(&P[r * 8 + sq * 4], make_float4(pp[0], pp[1], pp[2], pp[3]));
    }
    // rz0 = (r0, z0) partials
    {
        float vg[4];
        #pragma unroll
        for (int j = 0; j < 4; ++j) vg[j] = stid ? rr[j] * pp[j] : 0.f;
        #pragma unroll
        for (int off = 2; off < 64; off <<= 1)
            #pragma unroll
            for (int j = 0; j < 4; ++j) vg[j] += __shfl_xor(vg[j], off, 64);
        if (l < 2) {
            #pragma unroll
            for (int j = 0; j < 4; ++j) WP1[w][l * 4 + j] = vg[j];
        }
    }
    __syncthreads();                       // P + rz partials ready
    if (stid) {
        #pragma unroll
        for (int j = 0; j < 4; ++j) {
            float s = 0.f;
            #pragma unroll
            for (int w8 = 0; w8 < 8; ++w8) s += WP1[w8][sq * 4 + j];
            rz4[j] = s;
        }
    }

    const bool mact = (l < 50);
    const int gcol = mact ? l : 49;        // lanes 50..63: duplicate lane 49 (discarded)

    // ================= standard PCG main loop =================
    for (int k = 0; k < NITER; ++k) {
        __syncthreads();                   // B1: P stable, WP partials consumed

        // ---- matvec partials: acc[j][s] = sum_c G[row_j][c] * p[c][s] ----
        float acc[4][8];
        #pragma unroll
        for (int j = 0; j < 4; ++j)
            #pragma unroll
            for (int s = 0; s < 8; ++s) acc[j][s] = 0.f;

        for (int jc = w; jc < 25; jc += 8) {
            const float pv = P[jc * 64 + l];   // lane (dc,s) = (l>>3, l&7); ALL lanes load
            const float* __restrict__ gp = Gb + (size_t)(jc * 8) * KD + gcol;
            #pragma unroll
            for (int dc = 0; dc < 8; ++dc) {
                const float g0 = gp[0];
                const float g1 = gp[50];
                const float g2 = gp[100];
                const float g3 = gp[150];
                #pragma unroll
                for (int s = 0; s < 8; ++s) {
                    const float ps = rdlane(pv, dc * 8 + s);
                    acc[0][s] = fmaf(g0, ps, acc[0][s]);
                    acc[1][s] = fmaf(g1, ps, acc[1][s]);
                    acc[2][s] = fmaf(g2, ps, acc[2][s]);
                    acc[3][s] = fmaf(g3, ps, acc[3][s]);
                }
                gp += KD;
            }
        }
        if (mact) {
            #pragma unroll
            for (int j = 0; j < 4; ++j) {
                float* pw = &PART[w * (KD * 8) + (50 * j + l) * 8];
                st4(pw,     make_float4(acc[j][0], acc[j][1], acc[j][2], acc[j][3]));
                st4(pw + 4, make_float4(acc[j][4], acc[j][5], acc[j][6], acc[j][7]));
            }
        }
        __syncthreads();                   // B2: PART ready

        // ---- q = A p (combine) + pq partials ----
        float qq[4], vq[4];
        if (stid) {
            float4 sum = make_float4(0.f, 0.f, 0.f, 0.f);
            #pragma unroll
            for (int w8 = 0; w8 < 8; ++w8) {
                const float4 f = ld4(&PART[w8 * (KD * 8) + r * 8 + sq * 4]);
                sum.x += f.x; sum.y += f.y; sum.z += f.z; sum.w += f.w;
            }
            qq[0] = fmaf(lam[0], pp[0], sum.x);
            qq[1] = fmaf(lam[1], pp[1], sum.y);
            qq[2] = fmaf(lam[2], pp[2], sum.z);
            qq[3] = fmaf(lam[3], pp[3], sum.w);
            #pragma unroll
            for (int j = 0; j < 4; ++j) vq[j] = pp[j] * qq[j];
        } else {
            #pragma unroll
            for (int j = 0; j < 4; ++j) { qq[j] = 0.f; vq[j] = 0.f; }
        }
        #pragma unroll
        for (int off = 2; off < 64; off <<= 1)
            #pragma unroll
            for (int j = 0; j < 4; ++j) vq[j] += __shfl_xor(vq[j], off, 64);
        if (l < 2) {
            #pragma unroll
            for (int j = 0; j < 4; ++j) WP1[w][l * 4 + j] = vq[j];
        }
        __syncthreads();                   // B3: pq ready

        // ---- alpha, x/r update, rz partials ----
        float vr[4];
        if (stid) {
            #pragma unroll
            for (int j = 0; j < 4; ++j) {
                float pq = 0.f;
                #pragma unroll
                for (int w8 = 0; w8 < 8; ++w8) pq += WP1[w8][sq * 4 + j];
                const float alpha = rz4[j] / pq;
                xx[j] = fmaf(alpha, pp[j], xx[j]);
                rr[j] = fmaf(-alpha, qq[j], rr[j]);
                vr[j] = rr[j] * rr[j] * dinv[j];
            }
        } else {
            #pragma unroll
            for (int j = 0; j < 4; ++j) vr[j] = 0.f;
        }
        #pragma unroll
        for (int off = 2; off < 64; off <<= 1)
            #pragma unroll
            for (int j = 0; j < 4; ++j) vr[j] += __shfl_xor(vr[j], off, 64);
        if (l < 2) {
            #pragma unroll
            for (int j = 0; j < 4; ++j) WP2[w][l * 4 + j] = vr[j];
        }
        __syncthreads();                   // B4: rz ready

        // ---- beta, p update ----
        if (stid) {
            #pragma unroll
            for (int j = 0; j < 4; ++j) {
                float rzn = 0.f;
                #pragma unroll
                for (int w8 = 0; w8 < 8; ++w8) rzn += WP2[w8][sq * 4 + j];
                const float beta = rzn / rz4[j];
                rz4[j] = rzn;
                pp[j] = fmaf(beta, pp[j], rr[j] * dinv[j]);   // p = z + beta p
            }
            st4(&P[r * 8 + sq * 4], make_float4(pp[0], pp[1], pp[2], pp[3]));
        }
        // next iteration's B1 orders the P write vs the matvec read
    }

    // ---- store x ----
    if (stid) {
        float* __restrict__ Ob = out + (size_t)(bK + i0 + sq * 4) * KD + r;
        #pragma unroll
        for (int j = 0; j < 4; ++j)
            Ob[(size_t)j * KD] = xx[j];
    }
}

extern "C" void kernel_launch(void* const* d_in, const int* in_sizes, int n_in,
                              void* d_out, int out_size, void* d_ws, size_t ws_size,
                              hipStream_t stream) {
    const float* A  = (const float*)d_in[0];
    const float* B  = (const float*)d_in[1];
    const float* ex = (const float*)d_in[2];
    const float* ey = (const float*)d_in[3];
    float* out = (float*)d_out;

    float* G = (float*)d_ws;
    float* R = G + 8 * KD * KD;

    dim3 grid1(7, 7, 16);
    gemm_gr_kernel<<<grid1, 256, 0, stream>>>(A, B, G, R);

    cg_kernel<<<200, 512, 0, stream>>>(G, R, ex, ey, out);
}

// Round 12
// 253.650 us; speedup vs baseline: 2.2696x; 1.1784x over previous
//
#include <hip/hip_runtime.h>
#include <math.h>

#define KD 200
#define CD 352
#define NITER 32
#define LMB 0.01f

__device__ __forceinline__ float4 ld4(const float* p) { return *(const float4*)p; }
__device__ __forceinline__ void st4(float* p, float4 v) { *(float4*)p = v; }
__device__ __forceinline__ float rdlane(float v, int lane) {
    return __int_as_float(__builtin_amdgcn_readlane(__float_as_int(v), lane));
}

// ---------------- Kernel 1: G = A A^T, R = B A^T (batched, 64x64 tiles) ----------------
// k-major LDS (transposed at staging) so the inner loop is 2x ds_read_b128 + 16 FMA.
__global__ __launch_bounds__(256) void gemm_gr_kernel(
    const float* __restrict__ A, const float* __restrict__ B,
    float* __restrict__ G, float* __restrict__ R)
{
    __shared__ __align__(16) float Ms[16][72];   // [k][m], 288B row stride (16B aligned)
    __shared__ __align__(16) float Ns[16][72];   // [k][n]
    const int tid = threadIdx.x;
    const int z = blockIdx.z;
    const int b = z >> 1, which = z & 1;
    const float* __restrict__ Xb = (which ? B : A) + (size_t)b * KD * CD;
    const float* __restrict__ Ab = A + (size_t)b * KD * CD;
    float* __restrict__ O = (which ? R : G) + (size_t)b * KD * KD;
    const int tileM = blockIdx.y * 64;
    const int tileN = blockIdx.x * 64;

    // staging role: lane group of 4 covers one row's 16 k-values
    const int lm = tid >> 2;             // 0..63 (row within tile)
    const int kq = (tid & 3) * 4;        // 0,4,8,12 (k-quad within k-tile)
    const int rowM = min(tileM + lm, KD - 1);   // clamp: duplicate reads, stores guarded
    const int rowN = min(tileN + lm, KD - 1);
    const float* __restrict__ Xrow = Xb + (size_t)rowM * CD;
    const float* __restrict__ Arow = Ab + (size_t)rowN * CD;

    // compute role: 4x4 register tile
    const int ty = tid >> 4, tx = tid & 15;
    const int m0 = ty * 4, n0 = tx * 4;

    float acc[4][4] = {};
    for (int kk = 0; kk < CD; kk += 16) {
        const float4 vx = ld4(Xrow + kk + kq);
        const float4 va = ld4(Arow + kk + kq);
        __syncthreads();                 // previous compute done before overwrite
        Ms[kq + 0][lm] = vx.x; Ms[kq + 1][lm] = vx.y;
        Ms[kq + 2][lm] = vx.z; Ms[kq + 3][lm] = vx.w;
        Ns[kq + 0][lm] = va.x; Ns[kq + 1][lm] = va.y;
        Ns[kq + 2][lm] = va.z; Ns[kq + 3][lm] = va.w;
        __syncthreads();
        #pragma unroll
        for (int k = 0; k < 16; ++k) {
            const float4 am = ld4(&Ms[k][m0]);
            const float4 an = ld4(&Ns[k][n0]);
            acc[0][0] = fmaf(am.x, an.x, acc[0][0]);
            acc[0][1] = fmaf(am.x, an.y, acc[0][1]);
            acc[0][2] = fmaf(am.x, an.z, acc[0][2]);
            acc[0][3] = fmaf(am.x, an.w, acc[0][3]);
            acc[1][0] = fmaf(am.y, an.x, acc[1][0]);
            acc[1][1] = fmaf(am.y, an.y, acc[1][1]);
            acc[1][2] = fmaf(am.y, an.z, acc[1][2]);
            acc[1][3] = fmaf(am.y, an.w, acc[1][3]);
            acc[2][0] = fmaf(am.z, an.x, acc[2][0]);
            acc[2][1] = fmaf(am.z, an.y, acc[2][1]);
            acc[2][2] = fmaf(am.z, an.z, acc[2][2]);
            acc[2][3] = fmaf(am.z, an.w, acc[2][3]);
            acc[3][0] = fmaf(am.w, an.x, acc[3][0]);
            acc[3][1] = fmaf(am.w, an.y, acc[3][1]);
            acc[3][2] = fmaf(am.w, an.z, acc[3][2]);
            acc[3][3] = fmaf(am.w, an.w, acc[3][3]);
        }
    }
    // store 4x4 (gn multiples of 4; 200%4==0 -> float4 rows all-in or all-out)
    const int gn = tileN + n0;
    if (gn < KD) {
        #pragma unroll
        for (int i = 0; i < 4; ++i) {
            const int gm = tileM + m0 + i;
            if (gm < KD)
                st4(&O[(size_t)gm * KD + gn],
                    make_float4(acc[i][0], acc[i][1], acc[i][2], acc[i][3]));
        }
    }
}

// ------------- Kernel 2: batched standard PCG, 8 systems/block -------------
// Matvec (on p): lane l (l<50) of wave w owns rows {l, l+50, l+100, l+150}; wave w
// covers column-chunks jc = {w, w+8, w+16}; chunk 24's 8 columns are split one per
// wave (load balance). G reads coalesced (column-wise, symmetric); p broadcast via
// readlane->SGPR from one packed LDS read. BRANCH-FREE matvec loads (exec-mask/
// readlane hazard: guarding the P load breaks lanes 50..63 — see R9/R10).
// State thread tid<400 = (row r=tid>>1, quad sq=tid&1) keeps x,r,p,lam,dinv,rz
// for (row r, systems sq*4..sq*4+3) in REGISTERS. Direct dots (standard PCG).
__global__ __launch_bounds__(512) void cg_kernel(
    const float* __restrict__ G, const float* __restrict__ R,
    const float* __restrict__ ex, const float* __restrict__ ey,
    float* __restrict__ out)
{
    __shared__ __align__(16) float P[KD * 8];          // p[c][s]
    __shared__ __align__(16) float PART[8 * KD * 8];   // [w][row][s], 51.2 KB
    __shared__ float WP1[8][8];                        // pq (or rz0) partials [w][sq*4+j]
    __shared__ float WP2[8][8];                        // rz partials
    __shared__ float red8[8];

    const int tid = threadIdx.x;
    const int w = tid >> 6, l = tid & 63;
    const int blk = blockIdx.x;
    const int b = blk / 25;
    const int i0 = (blk - b * 25) * 8;
    const int bK = b * KD;
    const float* __restrict__ Gb = G + (size_t)b * KD * KD;

    // ---- scale = max(ex[b,:], ey[b,:]) ----
    float mxv = 0.f;
    if (tid < KD) mxv = fmaxf(ex[bK + tid], ey[bK + tid]);
    #pragma unroll
    for (int off = 32; off > 0; off >>= 1)
        mxv = fmaxf(mxv, __shfl_down(mxv, off, 64));
    if (l == 0) red8[w] = mxv;
    __syncthreads();
    float scale = red8[0];
    #pragma unroll
    for (int wv = 1; wv < 8; ++wv) scale = fmaxf(scale, red8[wv]);
    const float inv_scale = 1.0f / scale;

    // ---- state init (registers) ----
    const bool stid = tid < 400;
    const int r = tid >> 1, sq = tid & 1;
    float lam[4], dinv[4], rr[4], xx[4], pp[4], rz4[4];
    if (stid) {
        const float exj = ex[bK + r] * inv_scale;
        const float e1 = sqrtf(exj);
        const float gdiag = Gb[(size_t)r * KD + r];
        const float* __restrict__ Rb = R + (size_t)(bK + i0 + sq * 4) * KD + r;
        #pragma unroll
        for (int j = 0; j < 4; ++j) {
            const float eyi = ey[bK + i0 + sq * 4 + j] * inv_scale;
            const float e2 = sqrtf(eyi);
            const float dn = exj + eyi;
            const float re = e2 - e1;
            lam[j] = LMB * ((re * re + 1.f) / (dn * dn));
            dinv[j] = 1.f / (gdiag + lam[j]);
            rr[j] = Rb[(size_t)j * KD];
            pp[j] = rr[j] * dinv[j];      // p0 = z0
            xx[j] = 0.f;
        }
        st4(&P[r * 8 + sq * 4], make_float4(pp[0], pp[1], pp[2], pp[3]));
    }
    // rz0 = (r0, z0) partials
    {
        float vg[4];
        #pragma unroll
        for (int j = 0; j < 4; ++j) vg[j] = stid ? rr[j] * pp[j] : 0.f;
        #pragma unroll
        for (int off = 2; off < 64; off <<= 1)
            #pragma unroll
            for (int j = 0; j < 4; ++j) vg[j] += __shfl_xor(vg[j], off, 64);
        if (l < 2) {
            #pragma unroll
            for (int j = 0; j < 4; ++j) WP1[w][l * 4 + j] = vg[j];
        }
    }
    __syncthreads();                       // P + rz partials ready
    if (stid) {
        #pragma unroll
        for (int j = 0; j < 4; ++j) {
            float s = 0.f;
            #pragma unroll
            for (int w8 = 0; w8 < 8; ++w8) s += WP1[w8][sq * 4 + j];
            rz4[j] = s;
        }
    }

    const bool mact = (l < 50);
    const int gcol = mact ? l : 49;        // lanes 50..63: duplicate lane 49 (discarded)

    // ================= standard PCG main loop =================
    for (int k = 0; k < NITER; ++k) {
        __syncthreads();                   // B1: P stable, WP partials consumed

        // ---- matvec partials: acc[j][s] = sum_c G[c][row_j] * p[c][s] ----
        float acc[4][8];
        #pragma unroll
        for (int j = 0; j < 4; ++j)
            #pragma unroll
            for (int s = 0; s < 8; ++s) acc[j][s] = 0.f;

        for (int jc = w; jc < 24; jc += 8) {   // exactly 3 chunks per wave
            const float pv = P[jc * 64 + l];   // lane (dc,s) = (l>>3, l&7); ALL lanes load
            const float* __restrict__ gp = Gb + (size_t)(jc * 8) * KD + gcol;
            #pragma unroll
            for (int dc = 0; dc < 8; ++dc) {
                const float g0 = gp[0];
                const float g1 = gp[50];
                const float g2 = gp[100];
                const float g3 = gp[150];
                #pragma unroll
                for (int s = 0; s < 8; ++s) {
                    const float ps = rdlane(pv, dc * 8 + s);
                    acc[0][s] = fmaf(g0, ps, acc[0][s]);
                    acc[1][s] = fmaf(g1, ps, acc[1][s]);
                    acc[2][s] = fmaf(g2, ps, acc[2][s]);
                    acc[3][s] = fmaf(g3, ps, acc[3][s]);
                }
                gp += KD;
            }
        }
        {   // chunk 24 (c = 192..199): one column per wave
            const float pv24 = P[24 * 64 + l];
            const float* __restrict__ gp24 = Gb + (size_t)(192 + w) * KD + gcol;
            const float g0 = gp24[0];
            const float g1 = gp24[50];
            const float g2 = gp24[100];
            const float g3 = gp24[150];
            #pragma unroll
            for (int s = 0; s < 8; ++s) {
                const float ps = rdlane(pv24, w * 8 + s);
                acc[0][s] = fmaf(g0, ps, acc[0][s]);
                acc[1][s] = fmaf(g1, ps, acc[1][s]);
                acc[2][s] = fmaf(g2, ps, acc[2][s]);
                acc[3][s] = fmaf(g3, ps, acc[3][s]);
            }
        }
        if (mact) {
            #pragma unroll
            for (int j = 0; j < 4; ++j) {
                float* pw = &PART[w * (KD * 8) + (50 * j + l) * 8];
                st4(pw,     make_float4(acc[j][0], acc[j][1], acc[j][2], acc[j][3]));
                st4(pw + 4, make_float4(acc[j][4], acc[j][5], acc[j][6], acc[j][7]));
            }
        }
        __syncthreads();                   // B2: PART ready

        // ---- q = A p (combine) + pq partials ----
        float qq[4], vq[4];
        if (stid) {
            float4 sum = make_float4(0.f, 0.f, 0.f, 0.f);
            #pragma unroll
            for (int w8 = 0; w8 < 8; ++w8) {
                const float4 f = ld4(&PART[w8 * (KD * 8) + r * 8 + sq * 4]);
                sum.x += f.x; sum.y += f.y; sum.z += f.z; sum.w += f.w;
            }
            qq[0] = fmaf(lam[0], pp[0], sum.x);
            qq[1] = fmaf(lam[1], pp[1], sum.y);
            qq[2] = fmaf(lam[2], pp[2], sum.z);
            qq[3] = fmaf(lam[3], pp[3], sum.w);
            #pragma unroll
            for (int j = 0; j < 4; ++j) vq[j] = pp[j] * qq[j];
        } else {
            #pragma unroll
            for (int j = 0; j < 4; ++j) { qq[j] = 0.f; vq[j] = 0.f; }
        }
        #pragma unroll
        for (int off = 2; off < 64; off <<= 1)
            #pragma unroll
            for (int j = 0; j < 4; ++j) vq[j] += __shfl_xor(vq[j], off, 64);
        if (l < 2) {
            #pragma unroll
            for (int j = 0; j < 4; ++j) WP1[w][l * 4 + j] = vq[j];
        }
        __syncthreads();                   // B3: pq ready

        // ---- alpha, x/r update, rz partials ----
        float vr[4];
        if (stid) {
            #pragma unroll
            for (int j = 0; j < 4; ++j) {
                float pq = 0.f;
                #pragma unroll
                for (int w8 = 0; w8 < 8; ++w8) pq += WP1[w8][sq * 4 + j];
                const float alpha = rz4[j] / pq;
                xx[j] = fmaf(alpha, pp[j], xx[j]);
                rr[j] = fmaf(-alpha, qq[j], rr[j]);
                vr[j] = rr[j] * rr[j] * dinv[j];
            }
        } else {
            #pragma unroll
            for (int j = 0; j < 4; ++j) vr[j] = 0.f;
        }
        #pragma unroll
        for (int off = 2; off < 64; off <<= 1)
            #pragma unroll
            for (int j = 0; j < 4; ++j) vr[j] += __shfl_xor(vr[j], off, 64);
        if (l < 2) {
            #pragma unroll
            for (int j = 0; j < 4; ++j) WP2[w][l * 4 + j] = vr[j];
        }
        __syncthreads();                   // B4: rz ready

        // ---- beta, p update ----
        if (stid) {
            #pragma unroll
            for (int j = 0; j < 4; ++j) {
                float rzn = 0.f;
                #pragma unroll
                for (int w8 = 0; w8 < 8; ++w8) rzn += WP2[w8][sq * 4 + j];
                const float beta = rzn / rz4[j];
                rz4[j] = rzn;
                pp[j] = fmaf(beta, pp[j], rr[j] * dinv[j]);   // p = z + beta p
            }
            st4(&P[r * 8 + sq * 4], make_float4(pp[0], pp[1], pp[2], pp[3]));
        }
        // next iteration's B1 orders the P write vs the matvec read
    }

    // ---- store x ----
    if (stid) {
        float* __restrict__ Ob = out + (size_t)(bK + i0 + sq * 4) * KD + r;
        #pragma unroll
        for (int j = 0; j < 4; ++j)
            Ob[(size_t)j * KD] = xx[j];
    }
}

extern "C" void kernel_launch(void* const* d_in, const int* in_sizes, int n_in,
                              void* d_out, int out_size, void* d_ws, size_t ws_size,
                              hipStream_t stream) {
    const float* A  = (const float*)d_in[0];
    const float* B  = (const float*)d_in[1];
    const float* ex = (const float*)d_in[2];
    const float* ey = (const float*)d_in[3];
    float* out = (float*)d_out;

    float* G = (float*)d_ws;
    float* R = G + 8 * KD * KD;

    dim3 grid1(4, 4, 16);   // 64x64 tiles over 200x200, 8 batches x {G, R}
    gemm_gr_kernel<<<grid1, 256, 0, stream>>>(A, B, G, R);

    cg_kernel<<<200, 512, 0, stream>>>(G, R, ex, ey, out);
}